// Round 1
// baseline (76.680 us; speedup 1.0000x reference)
//
#include <hip/hip_runtime.h>
#include <hip/hip_bf16.h>

typedef __attribute__((ext_vector_type(8))) short short8;
typedef __attribute__((ext_vector_type(4))) float f32x4;

#define N_TOT 8192
#define HALF_B 4096
#define D 128
#define TEMP_INV 2.0f
#define NEG_BIG -1e30f
#define RPW 32        // rows per wave (two 16-row MFMA tiles)
#define CPB 1024      // columns per block (one slice)
#define NQ (N_TOT / CPB)   // 8 column slices

// round-to-nearest-even float -> bf16 bits (self-contained, no API dependency)
static __device__ inline unsigned short f2bf(float f) {
    unsigned int u = __builtin_bit_cast(unsigned int, f);
    u = (u + 0x7fffu + ((u >> 16) & 1u)) >> 16;
    return (unsigned short)u;
}

// ---------------- Kernel 1: L2-normalize rows, emit bf16 z [8192][128] ----
__global__ __launch_bounds__(256) void nrm_k(const float* __restrict__ pi,
                                             const float* __restrict__ pj,
                                             unsigned short* __restrict__ z) {
    int row  = (int)(blockIdx.x * 4) + (int)(threadIdx.x >> 6);
    int lane = (int)threadIdx.x & 63;
    const float* src = (row < HALF_B) ? (pi + (size_t)row * D)
                                      : (pj + (size_t)(row - HALF_B) * D);
    float2 v = *reinterpret_cast<const float2*>(src + lane * 2);
    float ss = v.x * v.x + v.y * v.y;
    #pragma unroll
    for (int off = 32; off >= 1; off >>= 1) ss += __shfl_xor(ss, off);
    float inv = 1.0f / fmaxf(sqrtf(ss), 1e-8f);
    unsigned int packed = ((unsigned int)f2bf(v.y * inv) << 16) | (unsigned int)f2bf(v.x * inv);
    *reinterpret_cast<unsigned int*>(z + (size_t)row * D + lane * 2) = packed;
}

// ---------------- Kernel 2: fused z@z^T + exp-sum + partner capture -------
// grid = (N_TOT/RPW, NQ), block = 64 (one wave).
__global__ __launch_bounds__(64) void sim_k(const unsigned short* __restrict__ z,
                                            float* __restrict__ s_part,
                                            float* __restrict__ p_part) {
    int lane = (int)threadIdx.x & 63;
    int r0   = (int)blockIdx.x * RPW;
    int cq   = (int)blockIdx.y;
    int c0   = cq * CPB;
    int lr   = lane & 15;     // row (A) / col (B) within 16-tile
    int kg   = lane >> 4;     // k-group: k = kg*8 + j
    size_t laneoff = (size_t)lr * D + (size_t)kg * 8;

    // A fragments for 32 rows x full K=128 held in registers (32 VGPRs)
    short8 a[2][4];
    #pragma unroll
    for (int t = 0; t < 2; ++t)
        #pragma unroll
        for (int kt = 0; kt < 4; ++kt)
            a[t][kt] = *reinterpret_cast<const short8*>(
                z + (size_t)(r0 + t * 16) * D + laneoff + (size_t)kt * 32);

    float s[2][4];
    float pv[2][4];
    #pragma unroll
    for (int t = 0; t < 2; ++t)
        #pragma unroll
        for (int r = 0; r < 4; ++r) { s[t][r] = 0.0f; pv[t][r] = NEG_BIG; }

    int rowbase = r0 + (lane >> 4) * 4;   // + t*16 + r gives global row

    for (int j0 = c0; j0 < c0 + CPB; j0 += 16) {
        short8 b[4];
        const unsigned short* bp = z + (size_t)j0 * D + laneoff;
        #pragma unroll
        for (int kt = 0; kt < 4; ++kt)
            b[kt] = *reinterpret_cast<const short8*>(bp + (size_t)kt * 32);
        int col = j0 + lr;
        #pragma unroll
        for (int t = 0; t < 2; ++t) {
            f32x4 acc = {0.0f, 0.0f, 0.0f, 0.0f};
            #pragma unroll
            for (int kt = 0; kt < 4; ++kt)
                acc = __builtin_amdgcn_mfma_f32_16x16x32_bf16(a[t][kt], b[kt], acc, 0, 0, 0);
            #pragma unroll
            for (int r = 0; r < 4; ++r) {
                int grow = rowbase + t * 16 + r;
                float v = acc[r] * TEMP_INV;          // sim/T, in [-2, 2]
                float e = __expf(v);
                if (col == grow) e = 0.0f;            // exclude diagonal k == i
                s[t][r] += e;
                if (col == (grow ^ HALF_B)) pv[t][r] = v;  // positive pair
            }
        }
    }

    // reduce across the 16 lanes (columns) of each k-group subgroup
    #pragma unroll
    for (int off = 1; off <= 8; off <<= 1) {
        #pragma unroll
        for (int t = 0; t < 2; ++t)
            #pragma unroll
            for (int r = 0; r < 4; ++r) {
                s[t][r] += __shfl_xor(s[t][r], off);
                pv[t][r] = fmaxf(pv[t][r], __shfl_xor(pv[t][r], off));
            }
    }
    if (lr == 0) {
        #pragma unroll
        for (int t = 0; t < 2; ++t)
            #pragma unroll
            for (int r = 0; r < 4; ++r) {
                int row = rowbase + t * 16 + r;
                s_part[(size_t)cq * N_TOT + row] = s[t][r];
                p_part[(size_t)cq * N_TOT + row] = pv[t][r];
            }
    }
}

// ---------------- Kernel 3: combine slices, log, deterministic sum --------
__global__ __launch_bounds__(1024) void red_k(const float* __restrict__ s_part,
                                              const float* __restrict__ p_part,
                                              float* __restrict__ out) {
    int tid = (int)threadIdx.x;
    float acc = 0.0f;
    for (int row = tid; row < N_TOT; row += 1024) {
        float S = 0.0f, P = NEG_BIG;
        #pragma unroll
        for (int q = 0; q < NQ; ++q) {
            S += s_part[(size_t)q * N_TOT + row];
            P = fmaxf(P, p_part[(size_t)q * N_TOT + row]);
        }
        acc += __logf(S) - P;
    }
    #pragma unroll
    for (int off = 32; off >= 1; off >>= 1) acc += __shfl_xor(acc, off);
    __shared__ float ls[16];
    int wid = tid >> 6;
    if ((tid & 63) == 0) ls[wid] = acc;
    __syncthreads();
    if (tid < 16) {
        float v = ls[tid];
        #pragma unroll
        for (int off = 8; off >= 1; off >>= 1) v += __shfl_xor(v, off);
        if (tid == 0) out[0] = v * (1.0f / (float)N_TOT);
    }
}

extern "C" void kernel_launch(void* const* d_in, const int* in_sizes, int n_in,
                              void* d_out, int out_size, void* d_ws, size_t ws_size,
                              hipStream_t stream) {
    const float* pi = (const float*)d_in[0];
    const float* pj = (const float*)d_in[1];
    float* out = (float*)d_out;

    unsigned short* z = (unsigned short*)d_ws;                       // 2 MiB
    float* s_part = (float*)((char*)d_ws + (size_t)N_TOT * D * 2);   // 256 KiB
    float* p_part = s_part + (size_t)NQ * N_TOT;                     // 256 KiB

    nrm_k<<<dim3(N_TOT / 4), dim3(256), 0, stream>>>(pi, pj, z);
    sim_k<<<dim3(N_TOT / RPW, NQ), dim3(64), 0, stream>>>(z, s_part, p_part);
    red_k<<<dim3(1), dim3(1024), 0, stream>>>(s_part, p_part, out);
}

// Round 2
// 54.559 us; speedup vs baseline: 1.4055x; 1.4055x over previous
//
#include <hip/hip_runtime.h>
#include <hip/hip_bf16.h>

typedef __attribute__((ext_vector_type(8))) short short8;
typedef __attribute__((ext_vector_type(4))) float f32x4;

#define N_TOT 8192
#define HALF_B 4096
#define D 128
#define RPW 64          // rows per wave
#define BROWS 256       // rows per block (4 waves)
#define CPB 256         // columns per block
#define NQ (N_TOT / CPB)   // 32 column slices
// scale so that (z*SCALE)@(z*SCALE)^T == sim * 2*log2(e); exp2 of that == exp(sim/T)
#define SCALE 1.6986437f
#define LN2 0.69314718f

#if __has_builtin(__builtin_amdgcn_exp2f)
  #define EXP2(x) __builtin_amdgcn_exp2f(x)
#else
  #define EXP2(x) exp2f(x)
#endif

// round-to-nearest-even float -> bf16 bits
static __device__ inline unsigned short f2bf(float f) {
    unsigned int u = __builtin_bit_cast(unsigned int, f);
    u = (u + 0x7fffu + ((u >> 16) & 1u)) >> 16;
    return (unsigned short)u;
}
static __device__ inline float bf2f(unsigned short b) {
    return __builtin_bit_cast(float, (unsigned int)b << 16);
}

// ---- Kernel 1: L2-normalize rows, scale, emit bf16 z2 [8192][128] --------
__global__ __launch_bounds__(256) void nrm_k(const float* __restrict__ pi,
                                             const float* __restrict__ pj,
                                             unsigned short* __restrict__ z) {
    int row  = (int)(blockIdx.x * 4) + (int)(threadIdx.x >> 6);
    int lane = (int)threadIdx.x & 63;
    const float* src = (row < HALF_B) ? (pi + (size_t)row * D)
                                      : (pj + (size_t)(row - HALF_B) * D);
    float2 v = *reinterpret_cast<const float2*>(src + lane * 2);
    float ss = v.x * v.x + v.y * v.y;
    #pragma unroll
    for (int off = 32; off >= 1; off >>= 1) ss += __shfl_xor(ss, off);
    float inv = SCALE / fmaxf(sqrtf(ss), 1e-8f);
    unsigned int packed = ((unsigned int)f2bf(v.y * inv) << 16) | (unsigned int)f2bf(v.x * inv);
    *reinterpret_cast<unsigned int*>(z + (size_t)row * D + lane * 2) = packed;
}

// ---- Kernel 2: pure stream z2@z2^T -> exp2 -> row partial sums -----------
// grid (N_TOT/BROWS, NQ), block 256 (4 waves, each owns 64 rows, shared cols)
__global__ __launch_bounds__(256) void sim_k(const unsigned short* __restrict__ z,
                                             float* __restrict__ s_part) {
    int lane = (int)threadIdx.x & 63;
    int wid  = (int)threadIdx.x >> 6;
    int r0   = (int)blockIdx.x * BROWS + wid * RPW;
    int cq   = (int)blockIdx.y;
    int c0   = cq * CPB;
    int lr   = lane & 15;     // A-row / B-col within 16-tile
    int kg   = lane >> 4;     // k-group
    size_t laneoff = (size_t)lr * D + (size_t)kg * 8;

    // A fragments: 64 rows x K=128 in registers (64 VGPRs)
    short8 a[4][4];
    #pragma unroll
    for (int t = 0; t < 4; ++t)
        #pragma unroll
        for (int kt = 0; kt < 4; ++kt)
            a[t][kt] = *reinterpret_cast<const short8*>(
                z + (size_t)(r0 + t * 16) * D + laneoff + (size_t)kt * 32);

    float s[4][4];
    #pragma unroll
    for (int t = 0; t < 4; ++t)
        #pragma unroll
        for (int r = 0; r < 4; ++r) s[t][r] = 0.0f;

    for (int j0 = c0; j0 < c0 + CPB; j0 += 16) {
        short8 b[4];
        const unsigned short* bp = z + (size_t)j0 * D + laneoff;
        #pragma unroll
        for (int kt = 0; kt < 4; ++kt)
            b[kt] = *reinterpret_cast<const short8*>(bp + (size_t)kt * 32);
        #pragma unroll
        for (int t = 0; t < 4; ++t) {
            f32x4 acc = {0.0f, 0.0f, 0.0f, 0.0f};
            #pragma unroll
            for (int kt = 0; kt < 4; ++kt)
                acc = __builtin_amdgcn_mfma_f32_16x16x32_bf16(a[t][kt], b[kt], acc, 0, 0, 0);
            #pragma unroll
            for (int r = 0; r < 4; ++r)
                s[t][r] += EXP2(acc[r]);   // includes diag; corrected in red1_k
        }
    }

    // reduce across the 16 columns held by each 16-lane group
    #pragma unroll
    for (int off = 1; off <= 8; off <<= 1)
        #pragma unroll
        for (int t = 0; t < 4; ++t)
            #pragma unroll
            for (int r = 0; r < 4; ++r)
                s[t][r] += __shfl_xor(s[t][r], off);

    if (lr == 0) {
        int rowbase = r0 + kg * 4;
        #pragma unroll
        for (int t = 0; t < 4; ++t)
            #pragma unroll
            for (int r = 0; r < 4; ++r)
                s_part[(size_t)cq * N_TOT + rowbase + t * 16 + r] = s[t][r];
    }
}

// ---- Kernel 3: per-row finish: S, diag, pos -> L_i; block partial sums ---
__global__ __launch_bounds__(256) void red1_k(const unsigned short* __restrict__ z,
                                              const float* __restrict__ s_part,
                                              float* __restrict__ partial) {
    int row = (int)blockIdx.x * 256 + (int)threadIdx.x;
    float S = 0.0f;
    #pragma unroll
    for (int q = 0; q < NQ; ++q) S += s_part[(size_t)q * N_TOT + row];

    const unsigned short* zr = z + (size_t)row * D;
    const unsigned short* zp = z + (size_t)(row ^ HALF_B) * D;
    float dacc = 0.0f, pacc = 0.0f;
    #pragma unroll
    for (int kt = 0; kt < 16; ++kt) {
        short8 va = *reinterpret_cast<const short8*>(zr + kt * 8);
        short8 vb = *reinterpret_cast<const short8*>(zp + kt * 8);
        #pragma unroll
        for (int j = 0; j < 8; ++j) {
            float fa = bf2f((unsigned short)va[j]);
            float fb = bf2f((unsigned short)vb[j]);
            dacc += fa * fa;
            pacc += fa * fb;
        }
    }
    // L_i = ln(S - exp2(diag)) - g_pos*ln2
    float Li = __logf(S - EXP2(dacc)) - pacc * LN2;

    // block reduction
    #pragma unroll
    for (int off = 32; off >= 1; off >>= 1) Li += __shfl_xor(Li, off);
    __shared__ float ls[4];
    int wid = (int)threadIdx.x >> 6;
    if ((threadIdx.x & 63) == 0) ls[wid] = Li;
    __syncthreads();
    if (threadIdx.x == 0)
        partial[blockIdx.x] = ls[0] + ls[1] + ls[2] + ls[3];
}

// ---- Kernel 4: final sum ------------------------------------------------
__global__ __launch_bounds__(64) void red2_k(const float* __restrict__ partial,
                                             float* __restrict__ out) {
    int lane = (int)threadIdx.x;
    float v = (lane < N_TOT / 256) ? partial[lane] : 0.0f;
    #pragma unroll
    for (int off = 32; off >= 1; off >>= 1) v += __shfl_xor(v, off);
    if (lane == 0) out[0] = v * (1.0f / (float)N_TOT);
}

extern "C" void kernel_launch(void* const* d_in, const int* in_sizes, int n_in,
                              void* d_out, int out_size, void* d_ws, size_t ws_size,
                              hipStream_t stream) {
    const float* pi = (const float*)d_in[0];
    const float* pj = (const float*)d_in[1];
    float* out = (float*)d_out;

    unsigned short* z = (unsigned short*)d_ws;                       // 2 MiB
    float* s_part = (float*)((char*)d_ws + (size_t)N_TOT * D * 2);   // 1 MiB
    float* partial = s_part + (size_t)NQ * N_TOT;                    // 128 B

    nrm_k<<<dim3(N_TOT / 4), dim3(256), 0, stream>>>(pi, pj, z);
    sim_k<<<dim3(N_TOT / BROWS, NQ), dim3(256), 0, stream>>>(z, s_part);
    red1_k<<<dim3(N_TOT / 256), dim3(256), 0, stream>>>(z, s_part, partial);
    red2_k<<<dim3(1), dim3(64), 0, stream>>>(partial, out);
}